// Round 1
// baseline (517.760 us; speedup 1.0000x reference)
//
#include <hip/hip_runtime.h>
#include <hip/hip_bf16.h>

// Problem constants (B=8, L=2048, D=512, N=1024, fp32)
constexpr int Dd   = 512;
constexpr int Nn   = 1024;
constexpr int Ttok = 16384;              // B*L
constexpr float DECAYc = 0.99f;

// GEMM tiling for the distance/argmin kernel
constexpr int BM = 64, BN = 64, BK = 32, PADc = 4;
constexpr int NSLICE = 4, NSL = Nn / NSLICE;   // 256 codes per slice

// ---------------------------------------------------------------- c_sq[n]
__global__ __launch_bounds__(64) void csq_kernel(const float* __restrict__ cb,
                                                 float* __restrict__ csq) {
  int n = blockIdx.x, lane = threadIdx.x;
  const float4* row = (const float4*)(cb + (size_t)n * Dd);
  float4 v0 = row[lane];
  float4 v1 = row[lane + 64];
  float s = v0.x*v0.x + v0.y*v0.y + v0.z*v0.z + v0.w*v0.w
          + v1.x*v1.x + v1.y*v1.y + v1.z*v1.z + v1.w*v1.w;
#pragma unroll
  for (int o = 32; o; o >>= 1) s += __shfl_down(s, o);
  if (lane == 0) csq[n] = s;
}

// ------------------------------------------- fused fp32 GEMM + partial argmin
// Block: 256 threads, computes 64 tokens x 256 codes (one N-slice), keeping a
// running (min score, index) per token. score = c_sq[n] - 2 * dot(x_t, c_n).
__global__ __launch_bounds__(256) void argmin_partial(
    const float* __restrict__ x, const float* __restrict__ cb,
    const float* __restrict__ csq,
    float* __restrict__ pv, int* __restrict__ pi) {
  __shared__ float Xs[BK][BM + PADc];
  __shared__ float Cs[BK][BN + PADc];
  __shared__ float rv[BM][16];
  __shared__ int   ri[BM][16];

  const int tid = threadIdx.x;
  const int ty = tid >> 4, tx = tid & 15;
  const int sl = blockIdx.x & (NSLICE - 1);
  const int tb = blockIdx.x >> 2;
  const int t0 = tb * BM;
  const int nbase = sl * NSL;

  // staging: thread -> (float4 column sc, row srow), 32 rows x 32 k per pass
  const int sc = tid & 7;        // float4 col within the 32-float K chunk
  const int srow = tid >> 3;     // 0..31

  float bv[4]; int bi[4];
#pragma unroll
  for (int i = 0; i < 4; ++i) { bv[i] = 3.4e38f; bi[i] = 0; }

  for (int nt = 0; nt < NSL / BN; ++nt) {
    const int n0 = nbase + nt * BN;
    float acc[4][4] = {{0.f,0.f,0.f,0.f},{0.f,0.f,0.f,0.f},
                       {0.f,0.f,0.f,0.f},{0.f,0.f,0.f,0.f}};
    for (int kc = 0; kc < Dd / BK; ++kc) {
      const int k0 = kc * BK;
      __syncthreads();
#pragma unroll
      for (int half = 0; half < 2; ++half) {
        const int r = srow + half * 32;
        float4 v = *(const float4*)(x  + (size_t)(t0 + r) * Dd + k0 + sc * 4);
        Xs[sc*4+0][r] = v.x; Xs[sc*4+1][r] = v.y;
        Xs[sc*4+2][r] = v.z; Xs[sc*4+3][r] = v.w;
        float4 c = *(const float4*)(cb + (size_t)(n0 + r) * Dd + k0 + sc * 4);
        Cs[sc*4+0][r] = c.x; Cs[sc*4+1][r] = c.y;
        Cs[sc*4+2][r] = c.z; Cs[sc*4+3][r] = c.w;
      }
      __syncthreads();
#pragma unroll
      for (int kk = 0; kk < BK; ++kk) {
        float4 a = *(const float4*)&Xs[kk][ty * 4];
        float4 b = *(const float4*)&Cs[kk][tx * 4];
        acc[0][0] = fmaf(a.x, b.x, acc[0][0]);
        acc[0][1] = fmaf(a.x, b.y, acc[0][1]);
        acc[0][2] = fmaf(a.x, b.z, acc[0][2]);
        acc[0][3] = fmaf(a.x, b.w, acc[0][3]);
        acc[1][0] = fmaf(a.y, b.x, acc[1][0]);
        acc[1][1] = fmaf(a.y, b.y, acc[1][1]);
        acc[1][2] = fmaf(a.y, b.z, acc[1][2]);
        acc[1][3] = fmaf(a.y, b.w, acc[1][3]);
        acc[2][0] = fmaf(a.z, b.x, acc[2][0]);
        acc[2][1] = fmaf(a.z, b.y, acc[2][1]);
        acc[2][2] = fmaf(a.z, b.z, acc[2][2]);
        acc[2][3] = fmaf(a.z, b.w, acc[2][3]);
        acc[3][0] = fmaf(a.w, b.x, acc[3][0]);
        acc[3][1] = fmaf(a.w, b.y, acc[3][1]);
        acc[3][2] = fmaf(a.w, b.z, acc[3][2]);
        acc[3][3] = fmaf(a.w, b.w, acc[3][3]);
      }
    }
    // fold this n-tile into the running argmin (ascending n => first-min wins)
#pragma unroll
    for (int j = 0; j < 4; ++j) {
      const int n = n0 + tx * 4 + j;
      const float cs = csq[n];
#pragma unroll
      for (int i = 0; i < 4; ++i) {
        float s = fmaf(-2.0f, acc[i][j], cs);
        if (s < bv[i]) { bv[i] = s; bi[i] = n; }
      }
    }
  }

  // cross-thread (tx) reduction per token row
#pragma unroll
  for (int i = 0; i < 4; ++i) { rv[ty*4+i][tx] = bv[i]; ri[ty*4+i][tx] = bi[i]; }
  __syncthreads();
  if (tid < BM) {
    float v = rv[tid][0]; int idx = ri[tid][0];
#pragma unroll
    for (int c = 1; c < 16; ++c) {
      float vv = rv[tid][c]; int ii = ri[tid][c];
      if (vv < v || (vv == v && ii < idx)) { v = vv; idx = ii; }
    }
    pv[(size_t)sl * Ttok + t0 + tid] = v;
    pi[(size_t)sl * Ttok + t0 + tid] = idx;
  }
}

// ------------------------------------ combine slices, emit idx, histogram
__global__ __launch_bounds__(256) void argmin_final(
    const float* __restrict__ pv, const int* __restrict__ pi,
    int* __restrict__ idx_out, float* __restrict__ idxf_out,
    float* __restrict__ hist) {
  int t = blockIdx.x * 256 + threadIdx.x;
  if (t >= Ttok) return;
  float v = pv[t]; int idx = pi[t];
#pragma unroll
  for (int s = 1; s < NSLICE; ++s) {
    float vv = pv[(size_t)s * Ttok + t]; int ii = pi[(size_t)s * Ttok + t];
    if (vv < v || (vv == v && ii < idx)) { v = vv; idx = ii; }
  }
  idx_out[t] = idx;
  idxf_out[t] = (float)idx;
  atomicAdd(&hist[idx], 1.0f);
}

// --------------------------------------------- dw[n] += x[t] scatter-add
__global__ __launch_bounds__(128) void dw_kernel(const float* __restrict__ x,
                                                 const int* __restrict__ idx,
                                                 float* __restrict__ dw) {
  const int t = blockIdx.x;
  const int d4 = threadIdx.x;            // 0..127
  float4 v = ((const float4*)(x + (size_t)t * Dd))[d4];
  const int n = idx[t];
  float* p = dw + (size_t)n * Dd + d4 * 4;
  atomicAdd(p + 0, v.x); atomicAdd(p + 1, v.y);
  atomicAdd(p + 2, v.z); atomicAdd(p + 3, v.w);
}

// -------- codebook_new = (decay*ema + (1-decay)*dw) / (decay*counts + (1-decay)*hist)
__global__ __launch_bounds__(256) void finalize_cb(
    const float* __restrict__ ema, const float* __restrict__ dw,
    const float* __restrict__ counts, const float* __restrict__ hist,
    float* __restrict__ cbnew) {
  int e4 = blockIdx.x * 256 + threadIdx.x;   // float4 index, 0..131071
  int n = e4 >> 7;
  float cnt = DECAYc * counts[n] + (1.0f - DECAYc) * hist[n];
  float inv = 1.0f / cnt;
  float4 e = ((const float4*)ema)[e4];
  float4 d = ((const float4*)dw)[e4];
  float4 o;
  o.x = (DECAYc * e.x + (1.0f - DECAYc) * d.x) * inv;
  o.y = (DECAYc * e.y + (1.0f - DECAYc) * d.y) * inv;
  o.z = (DECAYc * e.z + (1.0f - DECAYc) * d.z) * inv;
  o.w = (DECAYc * e.w + (1.0f - DECAYc) * d.w) * inv;
  ((float4*)cbnew)[e4] = o;
}

// ----------------------- quantized = gather(codebook_new, idx); loss partial
__global__ __launch_bounds__(256) void quant_loss(
    const float* __restrict__ x, const float* __restrict__ cbnew,
    const int* __restrict__ idx, float* __restrict__ out_q,
    float* __restrict__ loss) {
  float part = 0.f;
  const int total4 = Ttok * Dd / 4;
  for (int e4 = blockIdx.x * 256 + threadIdx.x; e4 < total4;
       e4 += gridDim.x * 256) {
    int t = e4 >> 7, d4 = e4 & 127;
    int n = idx[t];
    float4 q = ((const float4*)(cbnew + (size_t)n * Dd))[d4];
    float4 xv = ((const float4*)x)[e4];
    ((float4*)out_q)[e4] = q;
    float dx = xv.x - q.x, dy = xv.y - q.y, dz = xv.z - q.z, dw_ = xv.w - q.w;
    part += dx*dx + dy*dy + dz*dz + dw_*dw_;
  }
  __shared__ float red[4];
#pragma unroll
  for (int o = 32; o; o >>= 1) part += __shfl_down(part, o);
  int wid = threadIdx.x >> 6, lane = threadIdx.x & 63;
  if (lane == 0) red[wid] = part;
  __syncthreads();
  if (threadIdx.x == 0) {
    atomicAdd(loss, red[0] + red[1] + red[2] + red[3]);
  }
}

__global__ void loss_final(const float* __restrict__ loss,
                           float* __restrict__ out_loss) {
  // mean(0.5 * diff^2) = sum_sq * 0.5 / (T*D)
  *out_loss = loss[0] * (0.5f / (float)((size_t)Ttok * Dd));
}

// ---------------------------------------------------------------- launch
extern "C" void kernel_launch(void* const* d_in, const int* in_sizes, int n_in,
                              void* d_out, int out_size, void* d_ws, size_t ws_size,
                              hipStream_t stream) {
  const float* x      = (const float*)d_in[0];   // [T, D]
  const float* cb     = (const float*)d_in[1];   // [N, D]
  const float* ema    = (const float*)d_in[2];   // [N, D]
  const float* counts = (const float*)d_in[3];   // [N]

  float* out      = (float*)d_out;
  float* q_out    = out;                               // T*D
  float* loss_out = out + (size_t)Ttok * Dd;           // 1
  float* idxf_out = loss_out + 1;                      // T (indices as f32)

  // workspace layout (float offsets)
  float* ws    = (float*)d_ws;
  float* dw    = ws;                    // 524288  (zeroed)
  float* hist  = ws + 524288;           // 1024    (zeroed)
  float* loss  = ws + 525312;           // 4 incl pad (zeroed)
  float* csq   = ws + 525316;           // 1024
  float* cbnew = ws + 526340;           // 524288
  float* pv    = ws + 1050628;          // NSLICE*T = 65536
  int*   pi    = (int*)(ws + 1116164);  // 65536
  int*   idxb  = (int*)(ws + 1181700);  // 16384
  // total: 1,198,084 floats = 4.79 MB of ws

  // zero the accumulated regions (dw + hist + loss) every call
  hipMemsetAsync(dw, 0, (size_t)525316 * sizeof(float), stream);

  csq_kernel<<<Nn, 64, 0, stream>>>(cb, csq);
  argmin_partial<<<(Ttok / BM) * NSLICE, 256, 0, stream>>>(x, cb, csq, pv, pi);
  argmin_final<<<Ttok / 256, 256, 0, stream>>>(pv, pi, idxb, idxf_out, hist);
  dw_kernel<<<Ttok, 128, 0, stream>>>(x, idxb, dw);
  finalize_cb<<<(Nn * Dd / 4) / 256, 256, 0, stream>>>(ema, dw, counts, hist, cbnew);
  quant_loss<<<2048, 256, 0, stream>>>(x, cbnew, idxb, q_out, loss);
  loss_final<<<1, 1, 0, stream>>>(loss, loss_out);
}

// Round 3
// 261.267 us; speedup vs baseline: 1.9817x; 1.9817x over previous
//
#include <hip/hip_runtime.h>
#include <hip/hip_bf16.h>

constexpr int Dd   = 512;
constexpr int Nn   = 1024;
constexpr int Ttok = 16384;              // B*L
constexpr float DECAYc = 0.99f;
constexpr float MARGIN = 10.0f;

typedef short bf16x8 __attribute__((ext_vector_type(8)));
typedef float f32x4  __attribute__((ext_vector_type(4)));
typedef unsigned short us8v __attribute__((ext_vector_type(8)));

__device__ inline unsigned short f2bf(float f) {       // round-to-nearest-even
  unsigned int b = __float_as_uint(f);
  return (unsigned short)((b + 0x7FFFu + ((b >> 16) & 1u)) >> 16);
}
__device__ inline float bf2f(unsigned short u) {
  return __uint_as_float(((unsigned int)u) << 16);
}

// ------------------------------------------- codebook -> bf16, plus csq[n]
__global__ __launch_bounds__(64) void k_prep_cb(const float* __restrict__ cb,
                                                unsigned short* __restrict__ cbh,
                                                float* __restrict__ csq) {
  const int n = blockIdx.x, l = threadIdx.x;
  const float4* r = (const float4*)(cb + (size_t)n * Dd);
  float4 a = r[l], b = r[l + 64];
  float ss = a.x*a.x + a.y*a.y + a.z*a.z + a.w*a.w
           + b.x*b.x + b.y*b.y + b.z*b.z + b.w*b.w;
  ushort4 ua, ub;
  ua.x = f2bf(a.x); ua.y = f2bf(a.y); ua.z = f2bf(a.z); ua.w = f2bf(a.w);
  ub.x = f2bf(b.x); ub.y = f2bf(b.y); ub.z = f2bf(b.z); ub.w = f2bf(b.w);
  ((ushort4*)(cbh + (size_t)n * Dd))[l]      = ua;
  ((ushort4*)(cbh + (size_t)n * Dd))[l + 64] = ub;
#pragma unroll
  for (int o = 32; o; o >>= 1) ss += __shfl_down(ss, o);
  if (l == 0) csq[n] = ss;
}

// ---------------------- MFMA coarse-score GEMM: S[t][n] = csq[n] - 2*x.c
// A = codebook [1024x512] bf16 via global_load_lds; B = x [16384x512] fp32,
// converted to bf16 in-register during staging. 128x128 tile, BK=64, 4 waves.
__global__ __launch_bounds__(256) void k_gemm_scores(
    const unsigned short* __restrict__ cbh, const float* __restrict__ x,
    const float* __restrict__ csq, unsigned short* __restrict__ S) {
  __shared__ unsigned short As[128 * 64];    // codes
  __shared__ unsigned short Bs[128 * 64];    // tokens
  const int tid = threadIdx.x;
  const int w = tid >> 6, l = tid & 63;
  // XCD-aware bijective swizzle (1024 blocks, 1024 % 8 == 0)
  const int b = blockIdx.x;
  const int s = (b & 7) * 128 + (b >> 3);
  const int cm = s & 7;        // code-block  (M)
  const int tn = s >> 3;       // token-block (N)
  const int wr = w >> 1, wc = w & 1;

  const int srow = tid >> 3;             // 0..31 staging row
  const int scol = (tid & 7) * 8;        // element offset of the 8-elem chunk

  f32x4 acc[4][4] = {};

  const unsigned short* gA0 = cbh + (size_t)(cm * 128) * Dd;
  const float*          gB0 = x   + (size_t)(tn * 128) * Dd;

  for (int kc = 0; kc < Dd / 64; ++kc) {
    const int k0 = kc * 64;
    __syncthreads();                      // previous tile fully consumed
    // A: codebook bf16, direct global->LDS (wave-uniform base + lane*16B)
#pragma unroll
    for (int c = 0; c < 4; ++c) {
      const unsigned short* ga = gA0 + (size_t)(c * 32 + srow) * Dd + k0 + scol;
      char* la = (char*)As + c * 4096 + w * 1024;
      __builtin_amdgcn_global_load_lds((const __attribute__((address_space(1))) void*)ga,
                                       (__attribute__((address_space(3))) void*)la, 16, 0, 0);
    }
    // B: x fp32 -> bf16 in-register, ds_write_b128 (2-way bank alias = free)
#pragma unroll
    for (int p = 0; p < 4; ++p) {
      const int r = p * 32 + srow;
      const float* gb = gB0 + (size_t)r * Dd + k0 + scol;
      float4 v0 = *(const float4*)gb;
      float4 v1 = *(const float4*)(gb + 4);
      us8v o;
      o[0] = f2bf(v0.x); o[1] = f2bf(v0.y); o[2] = f2bf(v0.z); o[3] = f2bf(v0.w);
      o[4] = f2bf(v1.x); o[5] = f2bf(v1.y); o[6] = f2bf(v1.z); o[7] = f2bf(v1.w);
      *(us8v*)&Bs[r * 64 + scol] = o;
    }
    __syncthreads();                      // drains vmcnt+lgkmcnt before barrier
#pragma unroll
    for (int ks = 0; ks < 2; ++ks) {
      const int kb = ks * 32 + (l >> 4) * 8;
      const int ra = l & 15;
      bf16x8 af[4], bfr[4];
#pragma unroll
      for (int m = 0; m < 4; ++m)
        af[m] = *(const bf16x8*)&As[(wr * 64 + m * 16 + ra) * 64 + kb];
#pragma unroll
      for (int n = 0; n < 4; ++n)
        bfr[n] = *(const bf16x8*)&Bs[(wc * 64 + n * 16 + ra) * 64 + kb];
#pragma unroll
      for (int m = 0; m < 4; ++m)
#pragma unroll
        for (int n = 0; n < 4; ++n)
          acc[m][n] = __builtin_amdgcn_mfma_f32_16x16x32_bf16(af[m], bfr[n], acc[m][n], 0, 0, 0);
    }
  }

  // epilogue: lane holds 4 consecutive codes (C rows) for one token (C col)
  const int code0 = cm * 128 + wr * 64 + (l >> 4) * 4;
  const int tok0  = tn * 128 + wc * 64 + (l & 15);
#pragma unroll
  for (int m = 0; m < 4; ++m) {
    const int cd = code0 + m * 16;
    float4 cs = *(const float4*)&csq[cd];
#pragma unroll
    for (int n = 0; n < 4; ++n) {
      const int tk = tok0 + n * 16;
      ushort4 o;
      o.x = f2bf(cs.x - 2.0f * acc[m][n][0]);
      o.y = f2bf(cs.y - 2.0f * acc[m][n][1]);
      o.z = f2bf(cs.z - 2.0f * acc[m][n][2]);
      o.w = f2bf(cs.w - 2.0f * acc[m][n][3]);
      *(ushort4*)(S + (size_t)tk * Nn + cd) = o;
    }
  }
}

// ------------- per-token: coarse min over 1024, candidates, exact rescore
__global__ __launch_bounds__(256) void k_scan(
    const unsigned short* __restrict__ S, const float* __restrict__ x,
    const float* __restrict__ cb, const float* __restrict__ csq,
    int* __restrict__ idxb, float* __restrict__ idxf, float* __restrict__ hist) {
  __shared__ int candn[4][32];
  __shared__ int ccnt[4];
  const int tid = threadIdx.x, wid = tid >> 6, l = tid & 63;
  const int t = blockIdx.x * 4 + wid;

  const unsigned short* row = S + (size_t)t * Nn;
  us8v c0 = *(const us8v*)(row + l * 8);
  us8v c1 = *(const us8v*)(row + 512 + l * 8);
  float f0[8], f1[8];
  float minv = 3.4e38f; int mini = 0;
#pragma unroll
  for (int j = 0; j < 8; ++j) {
    f0[j] = bf2f(c0[j]);
    if (f0[j] < minv) { minv = f0[j]; mini = l * 8 + j; }
  }
#pragma unroll
  for (int j = 0; j < 8; ++j) {
    f1[j] = bf2f(c1[j]);
    if (f1[j] < minv) { minv = f1[j]; mini = 512 + l * 8 + j; }
  }
#pragma unroll
  for (int o = 1; o < 64; o <<= 1) {
    float ov = __shfl_xor(minv, o); int oi = __shfl_xor(mini, o);
    if (ov < minv || (ov == minv && oi < mini)) { minv = ov; mini = oi; }
  }
  if (l == 0) ccnt[wid] = 0;
  const float thr = minv + MARGIN;
#pragma unroll
  for (int j = 0; j < 8; ++j)
    if (f0[j] <= thr) { int p = atomicAdd(&ccnt[wid], 1); if (p < 32) candn[wid][p] = l * 8 + j; }
#pragma unroll
  for (int j = 0; j < 8; ++j)
    if (f1[j] <= thr) { int p = atomicAdd(&ccnt[wid], 1); if (p < 32) candn[wid][p] = 512 + l * 8 + j; }
  int nc = ccnt[wid]; if (nc > 32) nc = 32;

  int besti;
  if (nc == 1) {
    besti = candn[wid][0];
  } else {
    float bestv = 3.4e38f; besti = 0x7fffffff;
    const float4* xr = (const float4*)(x + (size_t)t * Dd);
    float4 xa = xr[l * 2], xb = xr[l * 2 + 1];
    for (int c = 0; c < nc; ++c) {
      int n = candn[wid][c];
      const float4* cr = (const float4*)(cb + (size_t)n * Dd);
      float4 ca = cr[l * 2], cb4 = cr[l * 2 + 1];
      float p = xa.x*ca.x + xa.y*ca.y + xa.z*ca.z + xa.w*ca.w
              + xb.x*cb4.x + xb.y*cb4.y + xb.z*cb4.z + xb.w*cb4.w;
#pragma unroll
      for (int o = 32; o; o >>= 1) p += __shfl_xor(p, o);
      float sc = csq[n] - 2.0f * p;               // exact fp32, same formula all cands
      if (sc < bestv || (sc == bestv && n < besti)) { bestv = sc; besti = n; }
    }
  }
  if (l == 0) {
    idxb[t] = besti;
    idxf[t] = (float)besti;
    atomicAdd(&hist[besti], 1.0f);
  }
}

// ---------------------------------------- prefix sum of histogram (1 block)
__global__ __launch_bounds__(1024) void k_offsets(const float* __restrict__ hist,
                                                  int* __restrict__ offs,
                                                  int* __restrict__ cursor) {
  __shared__ int sh[1024];
  const int tid = threadIdx.x;
  const int c = (int)hist[tid];
  sh[tid] = c; __syncthreads();
  for (int o = 1; o < 1024; o <<= 1) {
    int a = (tid >= o) ? sh[tid - o] : 0;
    __syncthreads();
    sh[tid] += a;
    __syncthreads();
  }
  const int excl = sh[tid] - c;
  offs[tid] = excl; cursor[tid] = excl;
}

// ------------------------------------------------ bucket tokens by index
__global__ __launch_bounds__(256) void k_scatter(const int* __restrict__ idxb,
                                                 int* __restrict__ cursor,
                                                 int* __restrict__ bucket) {
  int t = blockIdx.x * 256 + threadIdx.x;
  if (t < Ttok) {
    int n = idxb[t];
    int p = atomicAdd(&cursor[n], 1);
    bucket[p] = t;
  }
}

// ---- per-code: dw = sum of assigned x rows (coalesced), fused EMA epilogue
__global__ __launch_bounds__(512) void k_dw_cb(
    const float* __restrict__ x, const int* __restrict__ bucket,
    const int* __restrict__ offs, const float* __restrict__ hist,
    const float* __restrict__ ema, const float* __restrict__ counts,
    float* __restrict__ cbnew) {
  const int n = blockIdx.x, tid = threadIdx.x;
  const int st = offs[n];
  const float hc = hist[n];
  const int cnt = (int)hc;
  float a = 0.0f;
  for (int j = 0; j < cnt; ++j) {
    int t = bucket[st + j];
    a += x[(size_t)t * Dd + tid];
  }
  const float cn = DECAYc * counts[n] + (1.0f - DECAYc) * hc;
  cbnew[(size_t)n * Dd + tid] =
      (DECAYc * ema[(size_t)n * Dd + tid] + (1.0f - DECAYc) * a) / cn;
}

// ----------------------- quantized = gather(cbnew, idx); loss partial sums
__global__ __launch_bounds__(256) void quant_loss(
    const float* __restrict__ x, const float* __restrict__ cbnew,
    const int* __restrict__ idx, float* __restrict__ out_q,
    float* __restrict__ loss) {
  float part = 0.f;
  const int total4 = Ttok * Dd / 4;
  for (int e4 = blockIdx.x * 256 + threadIdx.x; e4 < total4;
       e4 += gridDim.x * 256) {
    int t = e4 >> 7, d4 = e4 & 127;
    int n = idx[t];
    float4 q = ((const float4*)(cbnew + (size_t)n * Dd))[d4];
    float4 xv = ((const float4*)x)[e4];
    ((float4*)out_q)[e4] = q;
    float dx = xv.x - q.x, dy = xv.y - q.y, dz = xv.z - q.z, dw_ = xv.w - q.w;
    part += dx*dx + dy*dy + dz*dz + dw_*dw_;
  }
  __shared__ float red[4];
#pragma unroll
  for (int o = 32; o; o >>= 1) part += __shfl_down(part, o);
  int wid = threadIdx.x >> 6, lane = threadIdx.x & 63;
  if (lane == 0) red[wid] = part;
  __syncthreads();
  if (threadIdx.x == 0) atomicAdd(loss, red[0] + red[1] + red[2] + red[3]);
}

__global__ void loss_final(const float* __restrict__ loss,
                           float* __restrict__ out_loss) {
  *out_loss = loss[0] * (0.5f / (float)((size_t)Ttok * Dd));
}

// ---------------------------------------------------------------- launch
extern "C" void kernel_launch(void* const* d_in, const int* in_sizes, int n_in,
                              void* d_out, int out_size, void* d_ws, size_t ws_size,
                              hipStream_t stream) {
  const float* x      = (const float*)d_in[0];
  const float* cb     = (const float*)d_in[1];
  const float* ema    = (const float*)d_in[2];
  const float* counts = (const float*)d_in[3];

  float* out      = (float*)d_out;
  float* q_out    = out;
  float* loss_out = out + (size_t)Ttok * Dd;
  float* idxf_out = loss_out + 1;
  // coarse score matrix S (bf16 [16384][1024] = 33.5 MB) aliases q_out;
  // fully consumed by k_scan before quant_loss overwrites it.
  unsigned short* S = (unsigned short*)q_out;

  // workspace layout (float offsets) — cbh is 1024*512 bf16 = 262144 FLOATS
  float* ws = (float*)d_ws;
  unsigned short* cbh = (unsigned short*)ws;           // [0, 262144)
  float* csq    = ws + 262144;                         // 1024
  float* hist   = ws + 263168;                         // 1024 (zeroed)
  float* loss   = ws + 264192;                         // 4    (zeroed)
  int*   offs   = (int*)(ws + 264196);                 // 1024
  int*   cursor = (int*)(ws + 265220);                 // 1024
  int*   bucket = (int*)(ws + 266244);                 // 16384
  int*   idxb   = (int*)(ws + 282628);                 // 16384
  float* cbnew  = ws + 299012;                         // 524288 -> ends 823300
  // total 823,300 floats = 3.29 MB (< round-1's working 4.79 MB)

  hipMemsetAsync(hist, 0, (size_t)(1024 + 4) * sizeof(float), stream);

  k_prep_cb<<<Nn, 64, 0, stream>>>(cb, cbh, csq);
  k_gemm_scores<<<(Nn / 128) * (Ttok / 128), 256, 0, stream>>>(cbh, x, csq, S);
  k_scan<<<Ttok / 4, 256, 0, stream>>>(S, x, cb, csq, idxb, idxf_out, hist);
  k_offsets<<<1, 1024, 0, stream>>>(hist, offs, cursor);
  k_scatter<<<Ttok / 256, 256, 0, stream>>>(idxb, cursor, bucket);
  k_dw_cb<<<Nn, 512, 0, stream>>>(x, bucket, offs, hist, ema, counts, cbnew);
  quant_loss<<<2048, 256, 0, stream>>>(x, cbnew, idxb, q_out, loss);
  loss_final<<<1, 1, 0, stream>>>(loss, loss_out);
}

// Round 4
// 135.480 us; speedup vs baseline: 3.8217x; 1.9285x over previous
//
#include <hip/hip_runtime.h>
#include <hip/hip_bf16.h>

constexpr int Dd   = 512;
constexpr int Nn   = 1024;
constexpr int Ttok = 16384;              // B*L
constexpr float DECAYc = 0.99f;
constexpr float MARGIN = 10.0f;
constexpr int CH = 16;                   // tokens per dw chunk

typedef short bf16x8 __attribute__((ext_vector_type(8)));
typedef float f32x4  __attribute__((ext_vector_type(4)));
typedef unsigned short us8v __attribute__((ext_vector_type(8)));

__device__ inline unsigned short f2bf(float f) {       // round-to-nearest-even
  unsigned int b = __float_as_uint(f);
  return (unsigned short)((b + 0x7FFFu + ((b >> 16) & 1u)) >> 16);
}
__device__ inline float bf2f(unsigned short u) {
  return __uint_as_float(((unsigned int)u) << 16);
}

// ------------------------------------------- codebook -> bf16, plus csq[n]
__global__ __launch_bounds__(64) void k_prep_cb(const float* __restrict__ cb,
                                                unsigned short* __restrict__ cbh,
                                                float* __restrict__ csq) {
  const int n = blockIdx.x, l = threadIdx.x;
  const float4* r = (const float4*)(cb + (size_t)n * Dd);
  float4 a = r[l], b = r[l + 64];
  float ss = a.x*a.x + a.y*a.y + a.z*a.z + a.w*a.w
           + b.x*b.x + b.y*b.y + b.z*b.z + b.w*b.w;
  ushort4 ua, ub;
  ua.x = f2bf(a.x); ua.y = f2bf(a.y); ua.z = f2bf(a.z); ua.w = f2bf(a.w);
  ub.x = f2bf(b.x); ub.y = f2bf(b.y); ub.z = f2bf(b.z); ub.w = f2bf(b.w);
  ((ushort4*)(cbh + (size_t)n * Dd))[l]      = ua;
  ((ushort4*)(cbh + (size_t)n * Dd))[l + 64] = ub;
#pragma unroll
  for (int o = 32; o; o >>= 1) ss += __shfl_down(ss, o);
  if (l == 0) csq[n] = ss;
}

// ---------------------- MFMA coarse-score GEMM: S[t][n] = csq[n] - 2*x.c
__global__ __launch_bounds__(256) void k_gemm_scores(
    const unsigned short* __restrict__ cbh, const float* __restrict__ x,
    const float* __restrict__ csq, unsigned short* __restrict__ S) {
  __shared__ unsigned short As[128 * 64];    // codes
  __shared__ unsigned short Bs[128 * 64];    // tokens
  const int tid = threadIdx.x;
  const int w = tid >> 6, l = tid & 63;
  const int b = blockIdx.x;
  const int s = (b & 7) * 128 + (b >> 3);    // XCD-aware bijective swizzle
  const int cm = s & 7;        // code-block  (M)
  const int tn = s >> 3;       // token-block (N)
  const int wr = w >> 1, wc = w & 1;

  const int srow = tid >> 3;             // 0..31 staging row
  const int scol = (tid & 7) * 8;        // element offset of the 8-elem chunk

  f32x4 acc[4][4] = {};

  const unsigned short* gA0 = cbh + (size_t)(cm * 128) * Dd;
  const float*          gB0 = x   + (size_t)(tn * 128) * Dd;

  for (int kc = 0; kc < Dd / 64; ++kc) {
    const int k0 = kc * 64;
    __syncthreads();
#pragma unroll
    for (int c = 0; c < 4; ++c) {
      const unsigned short* ga = gA0 + (size_t)(c * 32 + srow) * Dd + k0 + scol;
      char* la = (char*)As + c * 4096 + w * 1024;
      __builtin_amdgcn_global_load_lds((const __attribute__((address_space(1))) void*)ga,
                                       (__attribute__((address_space(3))) void*)la, 16, 0, 0);
    }
#pragma unroll
    for (int p = 0; p < 4; ++p) {
      const int r = p * 32 + srow;
      const float* gb = gB0 + (size_t)r * Dd + k0 + scol;
      float4 v0 = *(const float4*)gb;
      float4 v1 = *(const float4*)(gb + 4);
      us8v o;
      o[0] = f2bf(v0.x); o[1] = f2bf(v0.y); o[2] = f2bf(v0.z); o[3] = f2bf(v0.w);
      o[4] = f2bf(v1.x); o[5] = f2bf(v1.y); o[6] = f2bf(v1.z); o[7] = f2bf(v1.w);
      *(us8v*)&Bs[r * 64 + scol] = o;
    }
    __syncthreads();
#pragma unroll
    for (int ks = 0; ks < 2; ++ks) {
      const int kb = ks * 32 + (l >> 4) * 8;
      const int ra = l & 15;
      bf16x8 af[4], bfr[4];
#pragma unroll
      for (int m = 0; m < 4; ++m)
        af[m] = *(const bf16x8*)&As[(wr * 64 + m * 16 + ra) * 64 + kb];
#pragma unroll
      for (int n = 0; n < 4; ++n)
        bfr[n] = *(const bf16x8*)&Bs[(wc * 64 + n * 16 + ra) * 64 + kb];
#pragma unroll
      for (int m = 0; m < 4; ++m)
#pragma unroll
        for (int n = 0; n < 4; ++n)
          acc[m][n] = __builtin_amdgcn_mfma_f32_16x16x32_bf16(af[m], bfr[n], acc[m][n], 0, 0, 0);
    }
  }

  const int code0 = cm * 128 + wr * 64 + (l >> 4) * 4;
  const int tok0  = tn * 128 + wc * 64 + (l & 15);
#pragma unroll
  for (int m = 0; m < 4; ++m) {
    const int cd = code0 + m * 16;
    float4 cs = *(const float4*)&csq[cd];
#pragma unroll
    for (int n = 0; n < 4; ++n) {
      const int tk = tok0 + n * 16;
      ushort4 o;
      o.x = f2bf(cs.x - 2.0f * acc[m][n][0]);
      o.y = f2bf(cs.y - 2.0f * acc[m][n][1]);
      o.z = f2bf(cs.z - 2.0f * acc[m][n][2]);
      o.w = f2bf(cs.w - 2.0f * acc[m][n][3]);
      *(ushort4*)(S + (size_t)tk * Nn + cd) = o;
    }
  }
}

// ------------- per-token: coarse min over 1024, candidates, exact rescore
__global__ __launch_bounds__(256) void k_scan(
    const unsigned short* __restrict__ S, const float* __restrict__ x,
    const float* __restrict__ cb, const float* __restrict__ csq,
    int* __restrict__ idxb, float* __restrict__ idxf, float* __restrict__ hist) {
  __shared__ int candn[4][32];
  __shared__ int ccnt[4];
  const int tid = threadIdx.x, wid = tid >> 6, l = tid & 63;
  const int t = blockIdx.x * 4 + wid;

  const unsigned short* row = S + (size_t)t * Nn;
  us8v c0 = *(const us8v*)(row + l * 8);
  us8v c1 = *(const us8v*)(row + 512 + l * 8);
  float f0[8], f1[8];
  float minv = 3.4e38f; int mini = 0;
#pragma unroll
  for (int j = 0; j < 8; ++j) {
    f0[j] = bf2f(c0[j]);
    if (f0[j] < minv) { minv = f0[j]; mini = l * 8 + j; }
  }
#pragma unroll
  for (int j = 0; j < 8; ++j) {
    f1[j] = bf2f(c1[j]);
    if (f1[j] < minv) { minv = f1[j]; mini = 512 + l * 8 + j; }
  }
#pragma unroll
  for (int o = 1; o < 64; o <<= 1) {
    float ov = __shfl_xor(minv, o); int oi = __shfl_xor(mini, o);
    if (ov < minv || (ov == minv && oi < mini)) { minv = ov; mini = oi; }
  }
  if (l == 0) ccnt[wid] = 0;
  const float thr = minv + MARGIN;
#pragma unroll
  for (int j = 0; j < 8; ++j)
    if (f0[j] <= thr) { int p = atomicAdd(&ccnt[wid], 1); if (p < 32) candn[wid][p] = l * 8 + j; }
#pragma unroll
  for (int j = 0; j < 8; ++j)
    if (f1[j] <= thr) { int p = atomicAdd(&ccnt[wid], 1); if (p < 32) candn[wid][p] = 512 + l * 8 + j; }
  int nc = ccnt[wid]; if (nc > 32) nc = 32;

  int besti;
  if (nc == 1) {
    besti = candn[wid][0];
  } else {
    float bestv = 3.4e38f; besti = 0x7fffffff;
    const float4* xr = (const float4*)(x + (size_t)t * Dd);
    float4 xa = xr[l * 2], xb = xr[l * 2 + 1];
    for (int c = 0; c < nc; ++c) {
      int n = candn[wid][c];
      const float4* cr = (const float4*)(cb + (size_t)n * Dd);
      float4 ca = cr[l * 2], cb4 = cr[l * 2 + 1];
      float p = xa.x*ca.x + xa.y*ca.y + xa.z*ca.z + xa.w*ca.w
              + xb.x*cb4.x + xb.y*cb4.y + xb.z*cb4.z + xb.w*cb4.w;
#pragma unroll
      for (int o = 32; o; o >>= 1) p += __shfl_xor(p, o);
      float sc = csq[n] - 2.0f * p;
      if (sc < bestv || (sc == bestv && n < besti)) { bestv = sc; besti = n; }
    }
  }
  if (l == 0) {
    idxb[t] = besti;
    idxf[t] = (float)besti;
    atomicAdd(&hist[besti], 1.0f);
  }
}

// ---------------------------------------- prefix sum of histogram (1 block)
__global__ __launch_bounds__(1024) void k_offsets(const float* __restrict__ hist,
                                                  int* __restrict__ offs,
                                                  int* __restrict__ cursor) {
  __shared__ int sh[1024];
  const int tid = threadIdx.x;
  const int c = (int)hist[tid];
  sh[tid] = c; __syncthreads();
  for (int o = 1; o < 1024; o <<= 1) {
    int a = (tid >= o) ? sh[tid - o] : 0;
    __syncthreads();
    sh[tid] += a;
    __syncthreads();
  }
  const int excl = sh[tid] - c;
  offs[tid] = excl; cursor[tid] = excl;
}

// -------------------------------- bucket tokens by index (code-sorted order)
__global__ __launch_bounds__(256) void k_scatter(const int* __restrict__ idxb,
                                                 int* __restrict__ cursor,
                                                 int* __restrict__ bucket,
                                                 int* __restrict__ bcode) {
  int t = blockIdx.x * 256 + threadIdx.x;
  if (t < Ttok) {
    int n = idxb[t];
    int p = atomicAdd(&cursor[n], 1);
    bucket[p] = t;
    bcode[p] = n;
  }
}

// ------- load-balanced segmented sum: dw[n][d] += x rows of chunk segments
__global__ __launch_bounds__(512) void k_dw_part(
    const float* __restrict__ x, const int* __restrict__ bucket,
    const int* __restrict__ bcode, float* __restrict__ dw) {
  __shared__ int sh_t[CH], sh_n[CH];
  const int tid = threadIdx.x;
  const int p0 = blockIdx.x * CH;
  if (tid < CH) { sh_t[tid] = bucket[p0 + tid]; sh_n[tid] = bcode[p0 + tid]; }
  __syncthreads();
  float v[CH];
#pragma unroll
  for (int j = 0; j < CH; ++j)
    v[j] = x[(size_t)sh_t[j] * Dd + tid];    // 16 independent loads in flight
  float acc = v[0]; int cur = sh_n[0];       // segmented accumulate (uniform branch)
#pragma unroll
  for (int j = 1; j < CH; ++j) {
    int n = sh_n[j];
    if (n != cur) { atomicAdd(&dw[(size_t)cur * Dd + tid], acc); acc = 0.f; cur = n; }
    acc += v[j];
  }
  atomicAdd(&dw[(size_t)cur * Dd + tid], acc);
}

// -------- codebook_new = (decay*ema + (1-decay)*dw) / (decay*counts + (1-decay)*hist)
__global__ __launch_bounds__(256) void finalize_cb(
    const float* __restrict__ ema, const float* __restrict__ dw,
    const float* __restrict__ counts, const float* __restrict__ hist,
    float* __restrict__ cbnew) {
  int e4 = blockIdx.x * 256 + threadIdx.x;   // float4 index
  int n = e4 >> 7;
  float cnt = DECAYc * counts[n] + (1.0f - DECAYc) * hist[n];
  float inv = 1.0f / cnt;
  float4 e = ((const float4*)ema)[e4];
  float4 d = ((const float4*)dw)[e4];
  float4 o;
  o.x = (DECAYc * e.x + (1.0f - DECAYc) * d.x) * inv;
  o.y = (DECAYc * e.y + (1.0f - DECAYc) * d.y) * inv;
  o.z = (DECAYc * e.z + (1.0f - DECAYc) * d.z) * inv;
  o.w = (DECAYc * e.w + (1.0f - DECAYc) * d.w) * inv;
  ((float4*)cbnew)[e4] = o;
}

// ----------------------- quantized = gather(cbnew, idx); loss partial sums
__global__ __launch_bounds__(256) void quant_loss(
    const float* __restrict__ x, const float* __restrict__ cbnew,
    const int* __restrict__ idx, float* __restrict__ out_q,
    float* __restrict__ loss) {
  float part = 0.f;
  const int total4 = Ttok * Dd / 4;
  for (int e4 = blockIdx.x * 256 + threadIdx.x; e4 < total4;
       e4 += gridDim.x * 256) {
    int t = e4 >> 7, d4 = e4 & 127;
    int n = idx[t];
    float4 q = ((const float4*)(cbnew + (size_t)n * Dd))[d4];
    float4 xv = ((const float4*)x)[e4];
    ((float4*)out_q)[e4] = q;
    float dx = xv.x - q.x, dy = xv.y - q.y, dz = xv.z - q.z, dw_ = xv.w - q.w;
    part += dx*dx + dy*dy + dz*dz + dw_*dw_;
  }
  __shared__ float red[4];
#pragma unroll
  for (int o = 32; o; o >>= 1) part += __shfl_down(part, o);
  int wid = threadIdx.x >> 6, lane = threadIdx.x & 63;
  if (lane == 0) red[wid] = part;
  __syncthreads();
  if (threadIdx.x == 0) atomicAdd(loss, red[0] + red[1] + red[2] + red[3]);
}

__global__ void loss_final(const float* __restrict__ loss,
                           float* __restrict__ out_loss) {
  *out_loss = loss[0] * (0.5f / (float)((size_t)Ttok * Dd));
}

// ---------------------------------------------------------------- launch
extern "C" void kernel_launch(void* const* d_in, const int* in_sizes, int n_in,
                              void* d_out, int out_size, void* d_ws, size_t ws_size,
                              hipStream_t stream) {
  const float* x      = (const float*)d_in[0];
  const float* cb     = (const float*)d_in[1];
  const float* ema    = (const float*)d_in[2];
  const float* counts = (const float*)d_in[3];

  float* out      = (float*)d_out;
  float* q_out    = out;
  float* loss_out = out + (size_t)Ttok * Dd;
  float* idxf_out = loss_out + 1;
  // coarse score matrix S (bf16 [16384][1024] = 33.5 MB) aliases q_out;
  // fully consumed by k_scan before quant_loss overwrites it.
  unsigned short* S = (unsigned short*)q_out;

  // workspace layout (float offsets)
  float* ws = (float*)d_ws;
  unsigned short* cbh = (unsigned short*)ws;           // [0, 262144)  bf16 cb
  float* dw     = ws + 262144;                         // 524288 (zeroed)
  float* hist   = ws + 786432;                         // 1024   (zeroed)
  float* loss   = ws + 787456;                         // 4      (zeroed)
  float* csq    = ws + 787460;                         // 1024
  int*   offs   = (int*)(ws + 788484);                 // 1024
  int*   cursor = (int*)(ws + 789508);                 // 1024
  int*   bucket = (int*)(ws + 790532);                 // 16384
  int*   bcode  = (int*)(ws + 806916);                 // 16384
  int*   idxb   = (int*)(ws + 823300);                 // 16384
  float* cbnew  = ws + 839684;                         // 524288 -> ends 1363972
  // total 1,363,972 floats = 5.46 MB

  // zero dw + hist + loss (contiguous) every call
  hipMemsetAsync(dw, 0, (size_t)525316 * sizeof(float), stream);

  k_prep_cb<<<Nn, 64, 0, stream>>>(cb, cbh, csq);
  k_gemm_scores<<<(Nn / 128) * (Ttok / 128), 256, 0, stream>>>(cbh, x, csq, S);
  k_scan<<<Ttok / 4, 256, 0, stream>>>(S, x, cb, csq, idxb, idxf_out, hist);
  k_offsets<<<1, 1024, 0, stream>>>(hist, offs, cursor);
  k_scatter<<<Ttok / 256, 256, 0, stream>>>(idxb, cursor, bucket, bcode);
  k_dw_part<<<Ttok / CH, 512, 0, stream>>>(x, bucket, bcode, dw);
  finalize_cb<<<(Nn * Dd / 4) / 256, 256, 0, stream>>>(ema, dw, counts, hist, cbnew);
  quant_loss<<<2048, 256, 0, stream>>>(x, cbnew, idxb, q_out, loss);
  loss_final<<<1, 1, 0, stream>>>(loss, loss_out);
}